// Round 4
// baseline (120.135 us; speedup 1.0000x reference)
//
#include <hip/hip_runtime.h>
#include <math.h>

#define DD     768
#define NPIX   50176          // 224*224
#define NPIX4  12544          // NPIX/4
#define NBLK   1536           // 6 blocks/CU * 256 CU  -> fully co-resident
#define NMVB   160            // matvec partial blocks (48+48+48+16 chunks)
#define GLUEB  160            // glue block id

typedef float f4 __attribute__((ext_vector_type(4)));

// ---- workspace layout (float offsets) ----
#define WS_PART 0                     // 160 * 768 partials
#define WS_TBL  (NMVB*DD)             // 1538-entry channel table:
                                      // [0..767]=alpha*pos, [768]=sb,
                                      // [769..1536]=dec_vec, [1537]=ml
#define WS_SYNC (WS_TBL + 1544)       // 2 uints: ctr, flag (memset each call)

// ---- output layout (float offsets, tuple order concatenated) ----
// maps region O_SPM .. O_ML+NPIX is one contiguous 1538*NPIX block
#define O_PROMPT 0
#define O_SP     (O_PROMPT + DD)
#define O_SPM    (O_SP + DD)
#define O_SB     (O_SPM + (size_t)DD*NPIX)
#define O_DEC    (O_SB + NPIX)
#define O_ML     (O_DEC + (size_t)DD*NPIX)
#define O_ALPHA  (O_ML + NPIX)
#define O_NL     (O_ALPHA + 1)

__device__ __forceinline__ float gelu_exact(float x) {
    return 0.5f * x * (1.0f + erff(x * 0.70710678118654752f));
}
__device__ __forceinline__ float sigmoidf(float x) {
    return 1.0f / (1.0f + expf(-x));
}

__global__ __launch_bounds__(256, 6) void k_fused(
    const float* __restrict__ query, const float* __restrict__ pos,
    const float* __restrict__ neg,   const float* __restrict__ bnd,
    const float* __restrict__ alpha_w1, const float* __restrict__ alpha_b1,
    const float* __restrict__ alpha_w2, const float* __restrict__ alpha_b2,
    const float* __restrict__ neg_w1,   const float* __restrict__ neg_b1,
    const float* __restrict__ neg_w2,   const float* __restrict__ neg_b2,
    const float* __restrict__ prompt_w, const float* __restrict__ prompt_b,
    const float* __restrict__ dec_w,    const float* __restrict__ dec_b,
    const float* __restrict__ logit_w,  const float* __restrict__ logit_b,
    float* __restrict__ ws, float* __restrict__ out)
{
    const int b = blockIdx.x;
    const int t = threadIdx.x;
    unsigned* ctr  = (unsigned*)(ws + WS_SYNC);
    unsigned* flag = ctr + 1;

    if (b < NMVB) {
        // ---- phase A: matvec partials (48 K-rows per block, f4 along j) ----
        int m, c;
        if (b < 144) { m = b / 48; c = b % 48; }
        else         { m = 3;      c = b - 144; }
        const float* W = (m == 0) ? alpha_w1 : (m == 1) ? prompt_w
                       : (m == 2) ? dec_w    : neg_w1;
        const int k0 = c * 48;

        __shared__ float xs[48];
        if (t < 48) {
            int k = k0 + t;
            float v;
            if (m == 3)           v = neg[k];
            else if (k < DD)      v = pos[k];
            else if (k < 2 * DD)  v = neg[k - DD];
            else                  v = bnd[k - 2 * DD];
            xs[t] = v;
        }
        __syncthreads();

        if (t < 192) {
            const int j0 = 4 * t;
            f4 acc = {0.f, 0.f, 0.f, 0.f};
            const float* Wp = W + (size_t)k0 * DD + j0;
            #pragma unroll 8
            for (int kk = 0; kk < 48; ++kk)
                acc += xs[kk] * (*(const f4*)(Wp + (size_t)kk * DD));
            *(f4*)(ws + WS_PART + (size_t)b * DD + j0) = acc;
        }
        __syncthreads();
        if (t == 0) { __threadfence(); atomicAdd(ctr, 1u); }
    } else if (b == GLUEB) {
        // ---- phase B: glue (reduce partials, scalar chain, channel table) ----
        if (t == 0) {
            while (atomicAdd(ctr, 0u) < (unsigned)NMVB) __builtin_amdgcn_s_sleep(8);
            __threadfence();   // invalidate stale cached partials
        }
        __syncthreads();

        float r0 = 0.f, r1 = 0.f, r2 = 0.f, r3 = 0.f, r4 = 0.f;
        if (t < 192) {
            const int j0 = 4 * t;
            const float* P = ws + WS_PART;
            f4 ah = {0,0,0,0}, pr = {0,0,0,0}, dc = {0,0,0,0}, ng = {0,0,0,0};
            #pragma unroll 8
            for (int c = 0; c < 48; ++c) ah += *(const f4*)(P + (size_t)c * DD + j0);
            #pragma unroll 8
            for (int c = 0; c < 48; ++c) pr += *(const f4*)(P + (size_t)(48 + c) * DD + j0);
            #pragma unroll 8
            for (int c = 0; c < 48; ++c) dc += *(const f4*)(P + (size_t)(96 + c) * DD + j0);
            #pragma unroll 8
            for (int c = 0; c < 16; ++c) ng += *(const f4*)(P + (size_t)(144 + c) * DD + j0);

            pr += *(const f4*)(prompt_b + j0);
            const f4 dec_v = dc + *(const f4*)(dec_b + j0);
            *(f4*)(out + O_PROMPT + j0) = pr;       // prompt_tokens
            #pragma unroll
            for (int u = 0; u < 4; ++u)             // dec channel (odd offset)
                ws[WS_TBL + 769 + j0 + u] = dec_v[u];

            const f4 ab1  = *(const f4*)(alpha_b1 + j0);
            const f4 nb1  = *(const f4*)(neg_b1   + j0);
            const f4 aw2  = *(const f4*)(alpha_w2 + j0);
            const f4 nw2  = *(const f4*)(neg_w2   + j0);
            const f4 lw   = *(const f4*)(logit_w  + j0);
            const f4 negj = *(const f4*)(neg      + j0);
            const f4 bndj = *(const f4*)(bnd      + j0);
            #pragma unroll
            for (int u = 0; u < 4; ++u) {
                const float ga  = gelu_exact(ah[u] + ab1[u]);
                const float gn  = gelu_exact(ng[u] + nb1[u]);
                const float dbd = bndj[u] - negj[u];
                r0 += ga * aw2[u];
                r1 += gn * nw2[u];
                r2 += dec_v[u] * lw[u];
                r3 += negj[u] * lw[u];
                r4 += dbd * dbd;
            }
        }

        // butterfly reduce within each wave, then across 4 waves
        #pragma unroll
        for (int s = 32; s > 0; s >>= 1) {
            r0 += __shfl_xor(r0, s, 64);
            r1 += __shfl_xor(r1, s, 64);
            r2 += __shfl_xor(r2, s, 64);
            r3 += __shfl_xor(r3, s, 64);
            r4 += __shfl_xor(r4, s, 64);
        }
        __shared__ float red[5][4];
        __shared__ float sh_alpha;
        const int wid = t >> 6;
        if ((t & 63) == 0) {
            red[0][wid] = r0; red[1][wid] = r1; red[2][wid] = r2;
            red[3][wid] = r3; red[4][wid] = r4;
        }
        __syncthreads();
        if (t == 0) {
            float s0 = red[0][0] + red[0][1] + red[0][2] + red[0][3];
            float s1 = red[1][0] + red[1][1] + red[1][2] + red[1][3];
            float s2 = red[2][0] + red[2][1] + red[2][2] + red[2][3];
            float s3 = red[3][0] + red[3][1] + red[3][2] + red[3][3];
            float s4 = red[4][0] + red[4][1] + red[4][2] + red[4][3];
            const float alpha = sigmoidf(s0 + alpha_b2[0]);
            const float nl    = sigmoidf(s1 + neg_b2[0]);
            const float ld    = s2 + logit_b[0];
            const float ln    = s3 + logit_b[0];
            out[O_ALPHA]      = alpha;
            out[O_NL]         = nl;
            ws[WS_TBL + 768]  = sqrtf(s4);       // sb
            ws[WS_TBL + 1537] = ld - nl * ln;    // ml
            sh_alpha = alpha;
        }
        __syncthreads();
        if (t < 192) {
            const int j0 = 4 * t;
            const float alpha = sh_alpha;
            const f4 ap = alpha * (*(const f4*)(pos + j0));
            *(f4*)(out + O_SP + j0) = ap + (1.0f - alpha) * (*(const f4*)(query + j0));
            *(f4*)(ws + WS_TBL + j0) = ap;       // spm channel value
        }
        __syncthreads();
        if (t == 0) { __threadfence(); atomicExch(flag, 1u); }
    }

    // ---- phase C: all blocks wait for table, then flat broadcast fill ----
    if (t == 0) {
        while (atomicAdd(flag, 0u) == 0u) __builtin_amdgcn_s_sleep(8);
        __threadfence();   // invalidate stale cached table
    }
    __syncthreads();

    const float* tbl = ws + WS_TBL;
    f4* p = (f4*)(out + O_SPM);
    const unsigned total  = 1538u * NPIX4;       // 19,292,672 float4s
    const unsigned stride = NBLK * 256u;
    for (unsigned i = (unsigned)b * 256u + (unsigned)t; i < total; i += stride) {
        const unsigned c = i / NPIX4;            // magic-mul divide
        const float v = tbl[c];
        f4 v4 = {v, v, v, v};
        __builtin_nontemporal_store(v4, p + i);
    }
}

extern "C" void kernel_launch(void* const* d_in, const int* in_sizes, int n_in,
                              void* d_out, int out_size, void* d_ws, size_t ws_size,
                              hipStream_t stream) {
    const float* query    = (const float*)d_in[0];
    const float* pos      = (const float*)d_in[1];
    const float* neg      = (const float*)d_in[2];
    const float* bnd      = (const float*)d_in[3];
    // d_in[4] = spatial_map: values never used (shape-only in reference)
    const float* alpha_w1 = (const float*)d_in[5];
    const float* alpha_b1 = (const float*)d_in[6];
    const float* alpha_w2 = (const float*)d_in[7];
    const float* alpha_b2 = (const float*)d_in[8];
    const float* neg_w1   = (const float*)d_in[9];
    const float* neg_b1   = (const float*)d_in[10];
    const float* neg_w2   = (const float*)d_in[11];
    const float* neg_b2   = (const float*)d_in[12];
    const float* prompt_w = (const float*)d_in[13];
    const float* prompt_b = (const float*)d_in[14];
    const float* dec_w    = (const float*)d_in[15];
    const float* dec_b    = (const float*)d_in[16];
    const float* logit_w  = (const float*)d_in[17];
    const float* logit_b  = (const float*)d_in[18];

    float* out = (float*)d_out;
    float* ws  = (float*)d_ws;

    // zero the sync words (ctr, flag) — graph-capturable, deterministic per call
    hipMemsetAsync((char*)d_ws + (size_t)WS_SYNC * sizeof(float), 0,
                   2 * sizeof(unsigned), stream);

    k_fused<<<NBLK, 256, 0, stream>>>(
        query, pos, neg, bnd,
        alpha_w1, alpha_b1, alpha_w2, alpha_b2,
        neg_w1, neg_b1, neg_w2, neg_b2,
        prompt_w, prompt_b, dec_w, dec_b,
        logit_w, logit_b, ws, out);
}

// Round 5
// 81.851 us; speedup vs baseline: 1.4677x; 1.4677x over previous
//
#include <hip/hip_runtime.h>
#include <math.h>

#define DD     768
#define NPIX   50176          // 224*224
#define NPIX4  12544          // NPIX/4

typedef float f4 __attribute__((ext_vector_type(4)));

// ---- workspace layout (float offsets) ----
// 4 atomically-accumulated matvec result vectors (zeroed each call):
//   [0..767]=ah (fused@alpha_w1), [768..1535]=pr (fused@prompt_w),
//   [1536..2303]=dc (fused@dec_w), [2304..3071]=ng (neg@neg_w1)
#define WS_ACC 0

// ---- output layout (float offsets, tuple order concatenated) ----
// maps region O_SPM .. O_ML+NPIX is one contiguous 1538*NPIX block
#define O_PROMPT 0
#define O_SP     (O_PROMPT + DD)
#define O_SPM    (O_SP + DD)
#define O_SB     (O_SPM + (size_t)DD*NPIX)
#define O_DEC    (O_SB + NPIX)
#define O_ML     (O_DEC + (size_t)DD*NPIX)
#define O_ALPHA  (O_ML + NPIX)
#define O_NL     (O_ALPHA + 1)

__device__ __forceinline__ float gelu_exact(float x) {
    return 0.5f * x * (1.0f + erff(x * 0.70710678118654752f));
}
__device__ __forceinline__ float sigmoidf(float x) {
    return 1.0f / (1.0f + expf(-x));
}

// K1: matvec partials, atomically accumulated. grid=160, block=192.
// blocks 0..143: m = b/48 (0=alpha_w1,1=prompt_w,2=dec_w), chunk c = b%48
// blocks 144..159: m = 3 (neg_w1), chunk c = b-144
__global__ __launch_bounds__(192) void k_matvec(
    const float* __restrict__ pos, const float* __restrict__ neg,
    const float* __restrict__ bnd,
    const float* __restrict__ alpha_w1, const float* __restrict__ prompt_w,
    const float* __restrict__ dec_w,   const float* __restrict__ neg_w1,
    float* __restrict__ ws)
{
    const int b = blockIdx.x;
    const int t = threadIdx.x;
    int m, c;
    if (b < 144) { m = b / 48; c = b % 48; }
    else         { m = 3;      c = b - 144; }
    const float* W = (m == 0) ? alpha_w1 : (m == 1) ? prompt_w
                   : (m == 2) ? dec_w    : neg_w1;
    const int k0 = c * 48;

    __shared__ float xs[48];
    if (t < 48) {
        int k = k0 + t;
        float v;
        if (m == 3)           v = neg[k];
        else if (k < DD)      v = pos[k];
        else if (k < 2 * DD)  v = neg[k - DD];
        else                  v = bnd[k - 2 * DD];
        xs[t] = v;
    }
    __syncthreads();

    const int j0 = 4 * t;                     // 192 threads * 4 = 768 cols
    f4 acc = {0.f, 0.f, 0.f, 0.f};
    const float* Wp = W + (size_t)k0 * DD + j0;
    #pragma unroll 8
    for (int kk = 0; kk < 48; ++kk)
        acc += xs[kk] * (*(const f4*)(Wp + (size_t)kk * DD));

    float* dst = ws + WS_ACC + m * DD + j0;
    atomicAdd(dst + 0, acc[0]);
    atomicAdd(dst + 1, acc[1]);
    atomicAdd(dst + 2, acc[2]);
    atomicAdd(dst + 3, acc[3]);
}

// K2: glue (redundant per block) + flat broadcast fill. grid=2048, block=256.
__global__ __launch_bounds__(256) void k_fill(
    const float* __restrict__ query, const float* __restrict__ pos,
    const float* __restrict__ neg,   const float* __restrict__ bnd,
    const float* __restrict__ alpha_b1, const float* __restrict__ alpha_w2,
    const float* __restrict__ alpha_b2,
    const float* __restrict__ neg_b1,   const float* __restrict__ neg_w2,
    const float* __restrict__ neg_b2,
    const float* __restrict__ prompt_b, const float* __restrict__ dec_b,
    const float* __restrict__ logit_w,  const float* __restrict__ logit_b,
    const float* __restrict__ ws, float* __restrict__ out)
{
    const int b = blockIdx.x;
    const int t = threadIdx.x;

    __shared__ float tbl[1538];    // [0..767]=alpha*pos, [768]=sb,
                                   // [769..1536]=dec_vec, [1537]=ml
    __shared__ float red[5][4];
    __shared__ float sh[2];        // alpha, nl

    float r0 = 0.f, r1 = 0.f, r2 = 0.f, r3 = 0.f, r4 = 0.f;
    f4 dec_v = {0.f, 0.f, 0.f, 0.f};
    if (t < 192) {
        const int j0 = 4 * t;
        const f4 ah   = *(const f4*)(ws + WS_ACC          + j0);
        const f4 dc   = *(const f4*)(ws + WS_ACC + 2 * DD + j0);
        const f4 ng   = *(const f4*)(ws + WS_ACC + 3 * DD + j0);
        dec_v = dc + *(const f4*)(dec_b + j0);

        const f4 ab1  = *(const f4*)(alpha_b1 + j0);
        const f4 nb1  = *(const f4*)(neg_b1   + j0);
        const f4 aw2  = *(const f4*)(alpha_w2 + j0);
        const f4 nw2  = *(const f4*)(neg_w2   + j0);
        const f4 lw   = *(const f4*)(logit_w  + j0);
        const f4 negj = *(const f4*)(neg      + j0);
        const f4 bndj = *(const f4*)(bnd      + j0);
        #pragma unroll
        for (int u = 0; u < 4; ++u) {
            const float ga  = gelu_exact(ah[u] + ab1[u]);
            const float gn  = gelu_exact(ng[u] + nb1[u]);
            const float dbd = bndj[u] - negj[u];
            r0 += ga * aw2[u];
            r1 += gn * nw2[u];
            r2 += dec_v[u] * lw[u];
            r3 += negj[u] * lw[u];
            r4 += dbd * dbd;
        }
    }
    #pragma unroll
    for (int s = 32; s > 0; s >>= 1) {
        r0 += __shfl_xor(r0, s, 64);
        r1 += __shfl_xor(r1, s, 64);
        r2 += __shfl_xor(r2, s, 64);
        r3 += __shfl_xor(r3, s, 64);
        r4 += __shfl_xor(r4, s, 64);
    }
    const int wid = t >> 6;
    if ((t & 63) == 0) {
        red[0][wid] = r0; red[1][wid] = r1; red[2][wid] = r2;
        red[3][wid] = r3; red[4][wid] = r4;
    }
    __syncthreads();
    if (t == 0) {
        const float s0 = red[0][0] + red[0][1] + red[0][2] + red[0][3];
        const float s1 = red[1][0] + red[1][1] + red[1][2] + red[1][3];
        const float s2 = red[2][0] + red[2][1] + red[2][2] + red[2][3];
        const float s3 = red[3][0] + red[3][1] + red[3][2] + red[3][3];
        const float s4 = red[4][0] + red[4][1] + red[4][2] + red[4][3];
        const float alpha = sigmoidf(s0 + alpha_b2[0]);
        const float nl    = sigmoidf(s1 + neg_b2[0]);
        const float ld    = s2 + logit_b[0];
        const float ln    = s3 + logit_b[0];
        sh[0] = alpha;
        sh[1] = nl;
        tbl[768]  = sqrtf(s4);       // sb
        tbl[1537] = ld - nl * ln;    // ml
    }
    __syncthreads();

    const float alpha = sh[0];
    if (t < 192) {
        const int j0 = 4 * t;
        const f4 p4 = *(const f4*)(pos + j0);
        const f4 ap = alpha * p4;
        #pragma unroll
        for (int u = 0; u < 4; ++u) {
            tbl[j0 + u]       = ap[u];       // spm channel values
            tbl[769 + j0 + u] = dec_v[u];    // decoder channel values
        }
        if (b == 0) {   // small outputs, written once
            const f4 pr = *(const f4*)(ws + WS_ACC + DD + j0)
                        + *(const f4*)(prompt_b + j0);
            *(f4*)(out + O_PROMPT + j0) = pr;
            *(f4*)(out + O_SP + j0) =
                ap + (1.0f - alpha) * (*(const f4*)(query + j0));
            if (t == 0) {
                out[O_ALPHA] = alpha;
                out[O_NL]    = sh[1];
            }
        }
    }
    __syncthreads();

    // flat nontemporal broadcast fill of the contiguous 1538*NPIX region
    f4* p = (f4*)(out + O_SPM);
    const unsigned total  = 1538u * NPIX4;       // 19,292,672 float4s
    const unsigned stride = 2048u * 256u;
    for (unsigned i = (unsigned)b * 256u + (unsigned)t; i < total; i += stride) {
        const unsigned c = i / NPIX4;            // magic-mul divide
        const float v = tbl[c];
        f4 v4 = {v, v, v, v};
        __builtin_nontemporal_store(v4, p + i);
    }
}

extern "C" void kernel_launch(void* const* d_in, const int* in_sizes, int n_in,
                              void* d_out, int out_size, void* d_ws, size_t ws_size,
                              hipStream_t stream) {
    const float* query    = (const float*)d_in[0];
    const float* pos      = (const float*)d_in[1];
    const float* neg      = (const float*)d_in[2];
    const float* bnd      = (const float*)d_in[3];
    // d_in[4] = spatial_map: values never used (shape-only in reference)
    const float* alpha_w1 = (const float*)d_in[5];
    const float* alpha_b1 = (const float*)d_in[6];
    const float* alpha_w2 = (const float*)d_in[7];
    const float* alpha_b2 = (const float*)d_in[8];
    const float* neg_w1   = (const float*)d_in[9];
    const float* neg_b1   = (const float*)d_in[10];
    const float* neg_w2   = (const float*)d_in[11];
    const float* neg_b2   = (const float*)d_in[12];
    const float* prompt_w = (const float*)d_in[13];
    const float* prompt_b = (const float*)d_in[14];
    const float* dec_w    = (const float*)d_in[15];
    const float* dec_b    = (const float*)d_in[16];
    const float* logit_w  = (const float*)d_in[17];
    const float* logit_b  = (const float*)d_in[18];

    float* out = (float*)d_out;
    float* ws  = (float*)d_ws;

    // zero the 4 accumulator vectors (12 KB) — graph-capturable
    hipMemsetAsync(d_ws, 0, 4 * DD * sizeof(float), stream);

    // K1: matvec with atomic accumulation
    k_matvec<<<160, 192, 0, stream>>>(
        pos, neg, bnd, alpha_w1, prompt_w, dec_w, neg_w1, ws);

    // K2: per-block glue + flat broadcast fill
    k_fill<<<2048, 256, 0, stream>>>(
        query, pos, neg, bnd,
        alpha_b1, alpha_w2, alpha_b2,
        neg_b1, neg_w2, neg_b2,
        prompt_b, dec_b, logit_w, logit_b,
        ws, out);
}

// Round 6
// 70.101 us; speedup vs baseline: 1.7137x; 1.1676x over previous
//
#include <hip/hip_runtime.h>
#include <math.h>

#define DD     768
#define NPIX   50176          // 224*224
#define NPIX4  12544          // NPIX/4
#define NK     16             // K-chunks per matrix

typedef float f4 __attribute__((ext_vector_type(4)));

// ---- workspace layout (float offsets) ----
#define WS_PART 0                       // 4 mats * NK * 768 partials
#define WS_TBL  (4*NK*DD)               // 1538-entry channel-value table:
                                        // [0..767]=alpha*pos, [768]=sb,
                                        // [769..1536]=dec_vec, [1537]=ml

// ---- output layout (float offsets, tuple order concatenated) ----
// maps region O_SPM..O_ML+NPIX is one contiguous 1538*NPIX block
#define O_PROMPT 0
#define O_SP     (O_PROMPT + DD)
#define O_SPM    (O_SP + DD)
#define O_SB     (O_SPM + (size_t)DD*NPIX)
#define O_DEC    (O_SB + NPIX)
#define O_ML     (O_DEC + (size_t)DD*NPIX)
#define O_ALPHA  (O_ML + NPIX)
#define O_NL     (O_ALPHA + 1)

__device__ __forceinline__ float gelu_exact(float x) {
    return 0.5f * x * (1.0f + erff(x * 0.70710678118654752f));
}
__device__ __forceinline__ float sigmoidf(float x) {
    return 1.0f / (1.0f + expf(-x));
}

// K1: partial matvecs, float4 weight loads. grid=(NK,4), block=192.
// m: 0=alpha_h (fused@alpha_w1), 1=prompt (fused@prompt_w),
//    2=dec (fused@dec_w),        3=neg_h (neg@neg_w1)
// Each block: one (K-chunk, matrix); thread t covers cols j0=4t..4t+3.
__global__ __launch_bounds__(192) void k_matvec_part(
    const float* __restrict__ pos, const float* __restrict__ neg,
    const float* __restrict__ bnd,
    const float* __restrict__ alpha_w1, const float* __restrict__ prompt_w,
    const float* __restrict__ dec_w,   const float* __restrict__ neg_w1,
    float* __restrict__ ws)
{
    const int kchunk = blockIdx.x, m = blockIdx.y;
    const int t = threadIdx.x;

    const float* W = (m == 0) ? alpha_w1 : (m == 1) ? prompt_w
                   : (m == 2) ? dec_w    : neg_w1;

    __shared__ float xs[144];
    if (m == 3) {
        const int k0 = kchunk * 48;
        if (t < 48) xs[t] = neg[k0 + t];
    } else {
        const int k0 = kchunk * 144;
        if (t < 144) {
            int k = k0 + t;
            float v;
            if (k < DD)          v = pos[k];
            else if (k < 2 * DD) v = neg[k - DD];
            else                 v = bnd[k - 2 * DD];
            xs[t] = v;
        }
    }
    __syncthreads();

    const int j0 = 4 * t;
    f4 acc = {0.f, 0.f, 0.f, 0.f};
    if (m == 3) {
        const float* Wp = W + (size_t)(kchunk * 48) * DD + j0;
        #pragma unroll 16
        for (int kk = 0; kk < 48; ++kk)
            acc += xs[kk] * (*(const f4*)(Wp + (size_t)kk * DD));
    } else {
        const float* Wp = W + (size_t)(kchunk * 144) * DD + j0;
        #pragma unroll 16
        for (int kk = 0; kk < 144; ++kk)
            acc += xs[kk] * (*(const f4*)(Wp + (size_t)kk * DD));
    }

    *(f4*)(ws + WS_PART + (size_t)(m * NK + kchunk) * DD + j0) = acc;
}

// K2: one block of 768 threads (12 waves) — all scalar/vector glue.
__global__ __launch_bounds__(768) void k_small(
    const float* __restrict__ query, const float* __restrict__ pos,
    const float* __restrict__ neg,   const float* __restrict__ bnd,
    const float* __restrict__ alpha_b1, const float* __restrict__ alpha_w2,
    const float* __restrict__ alpha_b2,
    const float* __restrict__ neg_b1,   const float* __restrict__ neg_w2,
    const float* __restrict__ neg_b2,
    const float* __restrict__ prompt_b, const float* __restrict__ dec_b,
    const float* __restrict__ logit_w,  const float* __restrict__ logit_b,
    float* __restrict__ ws, float* __restrict__ out)
{
    const int j = threadIdx.x;  // 0..767

    // reduce K-chunk partials (coalesced, L2-hot)
    float a_h = 0.f, pr = 0.f, dc = 0.f, ng = 0.f;
    #pragma unroll
    for (int c = 0; c < NK; ++c) {
        a_h += ws[WS_PART + (0 * NK + c) * DD + j];
        pr  += ws[WS_PART + (1 * NK + c) * DD + j];
        dc  += ws[WS_PART + (2 * NK + c) * DD + j];
        ng  += ws[WS_PART + (3 * NK + c) * DD + j];
    }

    pr += prompt_b[j];
    const float dec_v = dc + dec_b[j];
    out[O_PROMPT + j]       = pr;     // prompt_tokens
    ws[WS_TBL + 769 + j]    = dec_v;  // decoder map channel value

    const float ga   = gelu_exact(a_h + alpha_b1[j]);
    const float gn   = gelu_exact(ng  + neg_b1[j]);
    const float negj = neg[j];
    const float lw   = logit_w[j];
    const float dbd  = bnd[j] - negj;

    float r[5];
    r[0] = ga * alpha_w2[j];
    r[1] = gn * neg_w2[j];
    r[2] = dec_v * lw;
    r[3] = negj * lw;
    r[4] = dbd * dbd;

    // per-wave butterfly reduction (64 lanes)
    #pragma unroll
    for (int s = 32; s > 0; s >>= 1) {
        #pragma unroll
        for (int q = 0; q < 5; ++q) r[q] += __shfl_xor(r[q], s, 64);
    }

    __shared__ float red[5][12];
    const int wid = j >> 6, lane = j & 63;
    if (lane == 0) {
        #pragma unroll
        for (int q = 0; q < 5; ++q) red[q][wid] = r[q];
    }
    __syncthreads();

    __shared__ float sh_alpha;
    if (j == 0) {
        float s[5];
        #pragma unroll
        for (int q = 0; q < 5; ++q) {
            float t = 0.f;
            #pragma unroll
            for (int w = 0; w < 12; ++w) t += red[q][w];
            s[q] = t;
        }
        const float alpha = sigmoidf(s[0] + alpha_b2[0]);
        const float nl    = sigmoidf(s[1] + neg_b2[0]);
        const float ld    = s[2] + logit_b[0];
        const float ln    = s[3] + logit_b[0];
        out[O_ALPHA]       = alpha;
        out[O_NL]          = nl;
        ws[WS_TBL + 768]   = sqrtf(s[4]);      // sb
        ws[WS_TBL + 1537]  = ld - nl * ln;     // ml
        sh_alpha = alpha;
    }
    __syncthreads();

    const float alpha = sh_alpha;
    const float ap    = alpha * pos[j];
    out[O_SP + j]  = ap + (1.0f - alpha) * query[j];  // semantic_prototype
    ws[WS_TBL + j] = ap;                              // spm channel value
}

// K3: flat broadcast fill of the 1538*NPIX contiguous map region.
// grid = 2048 blocks (8/CU, perfectly balanced), block = 256.
__global__ __launch_bounds__(256) void k_fill(
    const float* __restrict__ ws, float* __restrict__ out)
{
    const float* tbl = ws + WS_TBL;
    f4* p = (f4*)(out + O_SPM);
    const unsigned total  = 1538u * NPIX4;        // 19,292,672 float4s
    const unsigned stride = gridDim.x * 256u;
    for (unsigned i = blockIdx.x * 256u + threadIdx.x; i < total; i += stride) {
        const unsigned c = i / NPIX4;             // magic-mul divide
        const float v = tbl[c];
        f4 v4 = {v, v, v, v};
        __builtin_nontemporal_store(v4, p + i);
    }
}

extern "C" void kernel_launch(void* const* d_in, const int* in_sizes, int n_in,
                              void* d_out, int out_size, void* d_ws, size_t ws_size,
                              hipStream_t stream) {
    const float* query    = (const float*)d_in[0];
    const float* pos      = (const float*)d_in[1];
    const float* neg      = (const float*)d_in[2];
    const float* bnd      = (const float*)d_in[3];
    // d_in[4] = spatial_map: values never used (shape-only in reference)
    const float* alpha_w1 = (const float*)d_in[5];
    const float* alpha_b1 = (const float*)d_in[6];
    const float* alpha_w2 = (const float*)d_in[7];
    const float* alpha_b2 = (const float*)d_in[8];
    const float* neg_w1   = (const float*)d_in[9];
    const float* neg_b1   = (const float*)d_in[10];
    const float* neg_w2   = (const float*)d_in[11];
    const float* neg_b2   = (const float*)d_in[12];
    const float* prompt_w = (const float*)d_in[13];
    const float* prompt_b = (const float*)d_in[14];
    const float* dec_w    = (const float*)d_in[15];
    const float* dec_b    = (const float*)d_in[16];
    const float* logit_w  = (const float*)d_in[17];
    const float* logit_b  = (const float*)d_in[18];

    float* out = (float*)d_out;
    float* ws  = (float*)d_ws;

    // K1: partial matvecs (float4 weight loads)
    k_matvec_part<<<dim3(NK, 4), 192, 0, stream>>>(
        pos, neg, bnd, alpha_w1, prompt_w, dec_w, neg_w1, ws);

    // K2: reductions + scalar chain + small outputs + channel-value table
    k_small<<<1, DD, 0, stream>>>(
        query, pos, neg, bnd,
        alpha_b1, alpha_w2, alpha_b2,
        neg_b1, neg_w2, neg_b2,
        prompt_b, dec_b, logit_w, logit_b,
        ws, out);

    // K3: big broadcast fill (nontemporal, flat, balanced)
    k_fill<<<2048, 256, 0, stream>>>(ws, out);
}